// Round 1
// baseline (444.444 us; speedup 1.0000x reference)
//
#include <hip/hip_runtime.h>

typedef unsigned short u16;
typedef __bf16 bf16x8 __attribute__((ext_vector_type(8)));
typedef __bf16 bf16x4 __attribute__((ext_vector_type(4)));
typedef float floatx4 __attribute__((ext_vector_type(4)));
typedef u16 u16x4 __attribute__((ext_vector_type(4)));
typedef unsigned uint32x2 __attribute__((ext_vector_type(2)));
typedef unsigned uint32x4 __attribute__((ext_vector_type(4)));

#define MEG ((size_t)(1u << 20))

__device__ __forceinline__ u16 f2bf(float f) {
  unsigned int u = __float_as_uint(f);
  u += 0x7fffu + ((u >> 16) & 1u);   // round-to-nearest-even
  return (u16)(u >> 16);
}

// v_cvt_pk_bf16_f32: packs (lo,hi) -> one u32 of 2 bf16 (no builtin on gfx950)
__device__ __forceinline__ unsigned cvt_pk_bf16(float lo, float hi) {
  unsigned r;
  asm("v_cvt_pk_bf16_f32 %0, %1, %2" : "=v"(r) : "v"(lo), "v"(hi));
  return r;
}

// async global->LDS, 16B per lane; LDS dest = wave-uniform base + lane*16
__device__ __forceinline__ void load_lds16(const u16* g, u16* l) {
  __builtin_amdgcn_global_load_lds((const __attribute__((address_space(1))) unsigned int*)g,
                                   (__attribute__((address_space(3))) unsigned int*)l,
                                   16, 0, 0);
}

// ---------------- fp32 -> bf16 conversion of the 7 fp32 inputs ----------------
// layout (elements): [q 4M][k 4M][v 4M][Wq 1M][Wk 1M][Wv 1M][Wo 1M] = 16M
// 16 elems/thread (4 independent float4 loads) for memory-level parallelism.
__global__ __launch_bounds__(256) void cvt7(
    const float* __restrict__ s0, const float* __restrict__ s1,
    const float* __restrict__ s2, const float* __restrict__ s3,
    const float* __restrict__ s4, const float* __restrict__ s5,
    const float* __restrict__ s6, u16* __restrict__ dst)
{
  size_t e = ((size_t)blockIdx.x * 256 + threadIdx.x) * 16;
  unsigned m = (unsigned)(e >> 20);
  const float* s; size_t off;
  if (m < 4)       { s = s0; off = e; }
  else if (m < 8)  { s = s1; off = e - 4 * MEG; }
  else if (m < 12) { s = s2; off = e - 8 * MEG; }
  else if (m < 13) { s = s3; off = e - 12 * MEG; }
  else if (m < 14) { s = s4; off = e - 13 * MEG; }
  else if (m < 15) { s = s5; off = e - 14 * MEG; }
  else             { s = s6; off = e - 15 * MEG; }
  float4 f[4];
#pragma unroll
  for (int t = 0; t < 4; ++t)
    f[t] = *reinterpret_cast<const float4*>(s + off + t * 4);
#pragma unroll
  for (int t = 0; t < 4; ++t) {
    u16x4 o;
    o.x = f2bf(f[t].x); o.y = f2bf(f[t].y); o.z = f2bf(f[t].z); o.w = f2bf(f[t].w);
    *reinterpret_cast<u16x4*>(dst + e + t * 4) = o;
  }
}

// ---------------- generic C = A * B^T bf16 MFMA GEMM, BK=64 (projections) ----
// A: MxK bf16 row-major, B: NxK bf16 row-major. Tile 128x128, 4 waves (2x2).
// m-tile on blockIdx.x so consecutive dispatch ids share the B (weight) tile.
// xor-chunk-swizzled LDS (slot = c ^ (row&7)), conflict-free b128 frag reads.
// blockIdx.z==2 writes the transposed-per-head layout Vt[bh][d][l] instead.
__global__ __launch_bounds__(256) void gemm_proj(
    const u16* __restrict__ Abase, const u16* __restrict__ Bbase,
    u16* __restrict__ Cbase, u16* __restrict__ VtB,
    int K, long zA, long zB, long zC)
{
  __shared__ __align__(16) u16 As[128 * 64];
  __shared__ __align__(16) u16 Bs[128 * 64];
  const int tid = threadIdx.x;
  const int w = tid >> 6, ln = tid & 63;
  const int lm = ln & 15, lq = ln >> 4;
  const int wm = w >> 1, wn = w & 1;
  const long m0 = (long)blockIdx.x * 128, n0 = (long)blockIdx.y * 128;
  const u16* A = Abase + (size_t)blockIdx.z * (size_t)zA;
  const u16* B = Bbase + (size_t)blockIdx.z * (size_t)zB;

  const int r0 = tid >> 3;
  const int kc = (tid & 7) ^ (r0 & 7);
  const u16* gA = A + (m0 + r0) * (long)K + kc * 8;
  const u16* gB = B + (n0 + r0) * (long)K + kc * 8;
  const long rstep = 32L * K;

  const int sl0 = (lq ^ (lm & 7)) * 8;
  const int sl1 = ((4 + lq) ^ (lm & 7)) * 8;
  const u16* ab0 = &As[(wm * 64 + lm) * 64 + sl0];
  const u16* ab1 = &As[(wm * 64 + lm) * 64 + sl1];
  const u16* bb0 = &Bs[(wn * 64 + lm) * 64 + sl0];
  const u16* bb1 = &Bs[(wn * 64 + lm) * 64 + sl1];

  const floatx4 z4 = {0.f, 0.f, 0.f, 0.f};
  floatx4 acc[4][4];
#pragma unroll
  for (int i = 0; i < 4; ++i)
#pragma unroll
    for (int j = 0; j < 4; ++j) acc[i][j] = z4;

  for (int k0 = 0; k0 < K; k0 += 64) {
#pragma unroll
    for (int t = 0; t < 4; ++t) {
      load_lds16(gA + t * rstep, &As[(t * 256 + w * 64) * 8]);
      load_lds16(gB + t * rstep, &Bs[(t * 256 + w * 64) * 8]);
    }
    gA += 64; gB += 64;
    __syncthreads();
    bf16x8 af[4][2], bfr[4][2];
#pragma unroll
    for (int i = 0; i < 4; ++i) {
      af[i][0] = *reinterpret_cast<const bf16x8*>(ab0 + i * 1024);
      af[i][1] = *reinterpret_cast<const bf16x8*>(ab1 + i * 1024);
    }
#pragma unroll
    for (int j = 0; j < 4; ++j) {
      bfr[j][0] = *reinterpret_cast<const bf16x8*>(bb0 + j * 1024);
      bfr[j][1] = *reinterpret_cast<const bf16x8*>(bb1 + j * 1024);
    }
#pragma unroll
    for (int i = 0; i < 4; ++i)
#pragma unroll
      for (int j = 0; j < 4; ++j) {
        acc[i][j] = __builtin_amdgcn_mfma_f32_16x16x32_bf16(af[i][0], bfr[j][0], acc[i][j], 0, 0, 0);
        acc[i][j] = __builtin_amdgcn_mfma_f32_16x16x32_bf16(af[i][1], bfr[j][1], acc[i][j], 0, 0, 0);
      }
    __syncthreads();
  }

  if (blockIdx.z == 2) {
    // write V^T per head: Vt[(b*16+h)][d][l]; r=0..3 -> consecutive l -> one b64
#pragma unroll
    for (int i = 0; i < 4; ++i) {
      long row = m0 + wm * 64 + i * 16 + lq * 4;          // row = b*2048 + l
      int bq = (int)(row >> 11);
      int l  = (int)(row & 2047);
#pragma unroll
      for (int j = 0; j < 4; ++j) {
        long col = n0 + wn * 64 + j * 16 + lm;            // col = h*64 + d
        int hh = (int)(col >> 6), dd = (int)(col & 63);
        u16x4 o;
        o.x = f2bf(acc[i][j][0]); o.y = f2bf(acc[i][j][1]);
        o.z = f2bf(acc[i][j][2]); o.w = f2bf(acc[i][j][3]);
        *reinterpret_cast<u16x4*>(&VtB[((size_t)(bq * 16 + hh)) * 131072 +
                                       (size_t)dd * 2048 + l]) = o;
      }
    }
    return;
  }

#pragma unroll
  for (int i = 0; i < 4; ++i) {
    long row = m0 + wm * 64 + i * 16 + lq * 4;
#pragma unroll
    for (int j = 0; j < 4; ++j) {
      long col = n0 + wn * 64 + j * 16 + lm;
#pragma unroll
      for (int r = 0; r < 4; ++r) {
        size_t idx = (size_t)(row + r) * 1024 + (size_t)col;
        (Cbase + (size_t)blockIdx.z * (size_t)zC)[idx] = f2bf(acc[i][j][r]);
      }
    }
  }
}

// ---------------- out GEMM with FUSED K-split combine + normalize ------------
// C = ((OpA+OpB)*inv) @ Wo^T + bo, fp32 out. A K-tile (64) == one head h=k0>>6,
// so inv = 1/(psA[ql]+psB[ql]) is uniform per (row, k-iter): computed inline.
// A staged manually (load 2x b128 -> combine -> ds_write at DMA-equivalent
// swizzled slot); B staged via DMA. Tile 64x128, grid (64 m, 8 n).
__global__ __launch_bounds__(256) void gemm_out_fused(
    const u16* __restrict__ OpA, const u16* __restrict__ OpB,
    const float* __restrict__ psA, const float* __restrict__ psB,
    const u16* __restrict__ Wo, const float* __restrict__ bias,
    float* __restrict__ Cout)
{
  __shared__ __align__(16) u16 As[64 * 64];
  __shared__ __align__(16) u16 Bs[128 * 64];
  const int tid = threadIdx.x;
  const int w = tid >> 6, ln = tid & 63;
  const int lm = ln & 15, lq = ln >> 4;
  const int wm = w >> 1, wn = w & 1;
  const long m0 = (long)blockIdx.x * 64, n0 = (long)blockIdx.y * 128;

  const int r0 = tid >> 3;
  const int kc = (tid & 7) ^ (r0 & 7);
  const u16* gB = Wo + (n0 + r0) * 1024 + kc * 8;
  const long rstep = 32L * 1024;

  const int sl0 = (lq ^ (lm & 7)) * 8;
  const int sl1 = ((4 + lq) ^ (lm & 7)) * 8;
  const u16* ab0 = &As[(wm * 32 + lm) * 64 + sl0];
  const u16* ab1 = &As[(wm * 32 + lm) * 64 + sl1];
  const u16* bb0 = &Bs[(wn * 64 + lm) * 64 + sl0];
  const u16* bb1 = &Bs[(wn * 64 + lm) * 64 + sl1];

  // A-staging row info (2 rows per thread, 32 apart)
  int rowg[2]; int qlb[2];
#pragma unroll
  for (int t = 0; t < 2; ++t) {
    rowg[t] = (int)m0 + r0 + t * 32;                 // b*2048 + l
    int b = rowg[t] >> 11, l = rowg[t] & 2047;
    qlb[t] = (b << 4) * 2048 + l;                    // + h*2048 added per iter
  }

  const floatx4 z4 = {0.f, 0.f, 0.f, 0.f};
  floatx4 acc[2][4];
#pragma unroll
  for (int i = 0; i < 2; ++i)
#pragma unroll
    for (int j = 0; j < 4; ++j) acc[i][j] = z4;

  for (int k0 = 0; k0 < 1024; k0 += 64) {
    // B via DMA
#pragma unroll
    for (int t = 0; t < 4; ++t)
      load_lds16(gB + t * rstep, &Bs[(t * 256 + w * 64) * 8]);
    gB += 64;
    // A manual: combine K-split partials + normalize, write swizzled slot
    const int h = k0 >> 6;
#pragma unroll
    for (int t = 0; t < 2; ++t) {
      int ql = qlb[t] + h * 2048;
      float s = psA[ql] + psB[ql];
      float inv = (s > 0.f) ? __builtin_amdgcn_rcpf(s) : 0.f;
      size_t idx = (size_t)rowg[t] * 1024 + k0 + kc * 8;
      uint4 ua = *reinterpret_cast<const uint4*>(OpA + idx);
      uint4 ub = *reinterpret_cast<const uint4*>(OpB + idx);
      uint4 uo;
      const unsigned* pa = reinterpret_cast<const unsigned*>(&ua);
      const unsigned* pb = reinterpret_cast<const unsigned*>(&ub);
      unsigned* po = reinterpret_cast<unsigned*>(&uo);
#pragma unroll
      for (int i = 0; i < 4; ++i) {
        float alo = __uint_as_float(pa[i] << 16);
        float ahi = __uint_as_float(pa[i] & 0xFFFF0000u);
        float blo = __uint_as_float(pb[i] << 16);
        float bhi = __uint_as_float(pb[i] & 0xFFFF0000u);
        float olo = (alo + blo) * inv;
        float ohi = (ahi + bhi) * inv;
        po[i] = (unsigned)f2bf(olo) | ((unsigned)f2bf(ohi) << 16);
      }
      *reinterpret_cast<uint4*>(&As[(size_t)(t * 256 + tid) * 8]) = uo;
    }
    __syncthreads();
    bf16x8 af[2][2], bfr[4][2];
#pragma unroll
    for (int i = 0; i < 2; ++i) {
      af[i][0] = *reinterpret_cast<const bf16x8*>(ab0 + i * 1024);
      af[i][1] = *reinterpret_cast<const bf16x8*>(ab1 + i * 1024);
    }
#pragma unroll
    for (int j = 0; j < 4; ++j) {
      bfr[j][0] = *reinterpret_cast<const bf16x8*>(bb0 + j * 1024);
      bfr[j][1] = *reinterpret_cast<const bf16x8*>(bb1 + j * 1024);
    }
#pragma unroll
    for (int i = 0; i < 2; ++i)
#pragma unroll
      for (int j = 0; j < 4; ++j) {
        acc[i][j] = __builtin_amdgcn_mfma_f32_16x16x32_bf16(af[i][0], bfr[j][0], acc[i][j], 0, 0, 0);
        acc[i][j] = __builtin_amdgcn_mfma_f32_16x16x32_bf16(af[i][1], bfr[j][1], acc[i][j], 0, 0, 0);
      }
    __syncthreads();
  }

#pragma unroll
  for (int i = 0; i < 2; ++i) {
    long row = m0 + wm * 32 + i * 16 + lq * 4;
#pragma unroll
    for (int j = 0; j < 4; ++j) {
      long col = n0 + wn * 64 + j * 16 + lm;
      float bv = bias[col];
#pragma unroll
      for (int r = 0; r < 4; ++r)
        Cout[(size_t)(row + r) * 1024 + (size_t)col] = acc[i][j][r] + bv;
    }
  }
}

// ---------------- flash attention, K-split=2, double-buffered K/V ------------
// grid (16 q-tiles of 128, 32 bh, 2 K-halves) = 1024 blocks, 4 waves,
// 32 q-rows/wave (2 subtiles of 16), K-tile 64, 16 iters per block.
// NEW vs prior round:
//  - P stays IN REGISTER: S^T frag -> A-frag transpose via
//    v_cvt_pk_bf16_f32 + permlane32_swap + permlane16_swap (T12 pattern).
//    Ps LDS buffer (16 KB) + its bank conflicts + pack VALU are gone.
//  - K/V double-buffered (freed LDS): tile t+1 DMA issued at top of iter t,
//    drained by the single end-of-iter barrier -> full compute phase of
//    latency hiding, 1 barrier/iter instead of 2.
//  - s_setprio(1) around MFMA clusters (T5).
// LDS: 2*8KB K + 2*8KB V + 4KB mask = 36 KB -> 4 blocks/CU (unchanged).
__global__ __launch_bounds__(256, 4) void attn_kernel(
    const u16* __restrict__ Qp, const u16* __restrict__ Kp,
    const u16* __restrict__ Vt, const int* __restrict__ mask,
    u16* __restrict__ OpBase, float* __restrict__ psAB)
{
  __shared__ __align__(16) u16 Ks[2 * 64 * 64];   // 16 KB, slot = c ^ (key&7)
  __shared__ __align__(16) u16 Vts[2 * 64 * 64];  // 16 KB, slot = c ^ (d&7)
  __shared__ __align__(16) float mball[1024];     // 4 KB mask bias fp32 (0/-inf)

  const int tid = threadIdx.x;
  const int w = tid >> 6, ln = tid & 63;
  const int lm = ln & 15, lq = ln >> 4;
  const int bh = blockIdx.y, b = bh >> 4, h = bh & 15;
  const int q0 = blockIdx.x * 128;
  const int kz = blockIdx.z;

  const u16* Qh = Qp + (size_t)b * 2048 * 1024 + h * 64;
  const u16* Kh = Kp + (size_t)b * 2048 * 1024 + (size_t)kz * 1024 * 1024 + h * 64;
  const u16* Vth = Vt + (size_t)bh * 64 * 2048 + kz * 1024;
  u16* Op = OpBase + (size_t)kz * 8 * MEG;
  float* psZ = psAB + (size_t)kz * 65536;

  // mask bias staged once (first __syncthreads covers visibility)
  const int* mrowp = mask + b * 2048 + kz * 1024;
#pragma unroll
  for (int t = 0; t < 4; ++t) {
    int i = t * 256 + tid;
    mball[i] = (mrowp[i] != 0) ? 0.f : -__builtin_inff();
  }

  // persistent Q fragments (B-operand for S^T), 2 q-subtiles
  bf16x8 qf[2][2];
#pragma unroll
  for (int m = 0; m < 2; ++m) {
    int qrow = q0 + w * 32 + m * 16 + lm;
    qf[m][0] = *reinterpret_cast<const bf16x8*>(Qh + (size_t)qrow * 1024 + lq * 8);
    qf[m][1] = *reinterpret_cast<const bf16x8*>(Qh + (size_t)qrow * 1024 + 32 + lq * 8);
  }

  // loop-invariant LDS pointers
  const int sl0 = (lq ^ (lm & 7)) * 8;
  const int sl1 = ((4 + lq) ^ (lm & 7)) * 8;
  const u16* kb0 = &Ks[lm * 64 + sl0];
  const u16* kb1 = &Ks[lm * 64 + sl1];
  const u16* vb0 = &Vts[lm * 64 + sl0];
  const u16* vb1 = &Vts[lm * 64 + sl1];
  const float* mbi = mball + lq * 4;

  // staging source running pointers (row r0 = tid>>3, chunk kc = (tid&7)^(r0&7))
  const int r0 = tid >> 3;
  const int kc = (tid & 7) ^ (r0 & 7);
  const u16* gK0 = Kh + (size_t)r0 * 1024 + kc * 8;
  const u16* gK1 = gK0 + 32 * 1024;
  const u16* gV0 = Vth + (size_t)r0 * 2048 + kc * 8;
  const u16* gV1 = gV0 + 32 * 2048;

  const floatx4 z4 = {0.f, 0.f, 0.f, 0.f};
  floatx4 O[2][4];
#pragma unroll
  for (int m = 0; m < 2; ++m)
#pragma unroll
    for (int j = 0; j < 4; ++j) O[m][j] = z4;
  float psum[2] = {0.f, 0.f};
  const float SCL = 0.18033688011112042f;  // log2(e) / sqrt(64)

  // prologue: stage tile 0 -> buffer 0
  load_lds16(gK0, &Ks[(w * 64) * 8]);
  load_lds16(gK1, &Ks[(256 + w * 64) * 8]);
  load_lds16(gV0, &Vts[(w * 64) * 8]);
  load_lds16(gV1, &Vts[(256 + w * 64) * 8]);
  gK0 += 64 * 1024; gK1 += 64 * 1024; gV0 += 64; gV1 += 64;
  __syncthreads();

  for (int it = 0; it < 16; ++it) {
    const int cur = it & 1;
    // issue tile t+1 DMA into the other buffer; end-of-iter barrier drains it
    if (it < 15) {
      const int nx = (cur ^ 1) * 4096;
      load_lds16(gK0, &Ks[nx + (w * 64) * 8]);
      load_lds16(gK1, &Ks[nx + (256 + w * 64) * 8]);
      load_lds16(gV0, &Vts[nx + (w * 64) * 8]);
      load_lds16(gV1, &Vts[nx + (256 + w * 64) * 8]);
      gK0 += 64 * 1024; gK1 += 64 * 1024; gV0 += 64; gV1 += 64;
    }
    const int bofs = cur * 4096;

    // shared fragments for both q-subtiles
    bf16x8 kf[4][2], vf[4][2];
#pragma unroll
    for (int n = 0; n < 4; ++n) {
      kf[n][0] = *reinterpret_cast<const bf16x8*>(kb0 + bofs + n * 1024);
      kf[n][1] = *reinterpret_cast<const bf16x8*>(kb1 + bofs + n * 1024);
    }
#pragma unroll
    for (int j = 0; j < 4; ++j) {
      vf[j][0] = *reinterpret_cast<const bf16x8*>(vb0 + bofs + j * 1024);
      vf[j][1] = *reinterpret_cast<const bf16x8*>(vb1 + bofs + j * 1024);
    }
    float4 mb4[4];
#pragma unroll
    for (int n = 0; n < 4; ++n)
      mb4[n] = *reinterpret_cast<const float4*>(mbi + n * 16);
    mbi += 64;

#pragma unroll
    for (int m = 0; m < 2; ++m) {
      // S^T = K_tile * Q^T : D[key_local = lq*4+r][q = lm]
      floatx4 S[4];
      __builtin_amdgcn_s_setprio(1);
#pragma unroll
      for (int n = 0; n < 4; ++n) {
        S[n] = __builtin_amdgcn_mfma_f32_16x16x32_bf16(kf[n][0], qf[m][0], z4, 0, 0, 0);
        S[n] = __builtin_amdgcn_mfma_f32_16x16x32_bf16(kf[n][1], qf[m][1], S[n], 0, 0, 0);
      }
      __builtin_amdgcn_s_setprio(0);

      // p = exp2(S*SCL + maskbias); pack to bf16 pairs; in-register transpose:
      // lane holds c[n][j] = P[q=lm][key 16n+4lq+{2j,2j+1}]; A-frag needs
      // pf[h2] = P[q=lm][key 32h2+8lq+e].  For each (h2,j):
      //   (P,Q) = permlane32_swap(c[2h2][j], c[2h2+1][j])
      //   (W[j], W[2+j]) = permlane16_swap(P, Q)
#pragma unroll
      for (int h2 = 0; h2 < 2; ++h2) {
        unsigned cc[2][2];
#pragma unroll
        for (int nn = 0; nn < 2; ++nn) {
          const int n = 2 * h2 + nn;
          float p0 = __builtin_amdgcn_exp2f(fmaf(S[n][0], SCL, mb4[n].x));
          float p1 = __builtin_amdgcn_exp2f(fmaf(S[n][1], SCL, mb4[n].y));
          float p2 = __builtin_amdgcn_exp2f(fmaf(S[n][2], SCL, mb4[n].z));
          float p3 = __builtin_amdgcn_exp2f(fmaf(S[n][3], SCL, mb4[n].w));
          psum[m] += (p0 + p1) + (p2 + p3);
          cc[nn][0] = cvt_pk_bf16(p0, p1);
          cc[nn][1] = cvt_pk_bf16(p2, p3);
        }
        unsigned W[4];
#pragma unroll
        for (int j = 0; j < 2; ++j) {
          uint32x2 t1 = __builtin_amdgcn_permlane32_swap(cc[0][j], cc[1][j], false, false);
          uint32x2 t2 = __builtin_amdgcn_permlane16_swap(t1.x, t1.y, false, false);
          W[j] = t2.x; W[2 + j] = t2.y;
        }
        uint32x4 wv = {W[0], W[1], W[2], W[3]};
        bf16x8 pf = __builtin_bit_cast(bf16x8, wv);
        __builtin_amdgcn_s_setprio(1);
#pragma unroll
        for (int j = 0; j < 4; ++j)
          O[m][j] = __builtin_amdgcn_mfma_f32_16x16x32_bf16(pf, vf[j][h2], O[m][j], 0, 0, 0);
        __builtin_amdgcn_s_setprio(0);
      }
    }
    __syncthreads();
  }

  // epilogue: reduce psum over lq bits -> per-q total for this K-half;
  // store psum (lanes lq==0, consecutive rows -> coalesced) + raw O (bf16)
#pragma unroll
  for (int m = 0; m < 2; ++m) {
    float s = psum[m];
    s += __shfl_xor(s, 16, 64);
    s += __shfl_xor(s, 32, 64);
    int prow = q0 + w * 32 + m * 16 + lm;
    if (lq == 0) psZ[bh * 2048 + prow] = s;
#pragma unroll
    for (int r = 0; r < 4; ++r) {
      int row = q0 + w * 32 + m * 16 + lq * 4 + r;
      size_t base = ((size_t)b * 2048 + row) * 1024 + h * 64 + lm;
#pragma unroll
      for (int j = 0; j < 4; ++j)
        Op[base + j * 16] = f2bf(O[m][j][r]);
    }
  }
}

// ---------------- host ----------------
extern "C" void kernel_launch(void* const* d_in, const int* in_sizes, int n_in,
                              void* d_out, int out_size, void* d_ws, size_t ws_size,
                              hipStream_t stream) {
  const float* q  = (const float*)d_in[0];
  const float* k  = (const float*)d_in[1];
  const float* v  = (const float*)d_in[2];
  const int*   mk = (const int*)  d_in[3];
  const float* wq = (const float*)d_in[4];
  const float* wk = (const float*)d_in[5];
  const float* wv = (const float*)d_in[6];
  const float* wo = (const float*)d_in[7];
  const float* bo = (const float*)d_in[8];

  u16* ws16 = (u16*)d_ws;
  // element offsets (bf16): Xq=0 Xk=4M Xv=8M | Wq=12M Wk=13M Wv=14M Wo=15M
  // Qp=16M Kp=20M Vt=24M.
  // After proj: Xq/Xv/Wq..Wv dead -> OpA=0..4M, OpB=8..12M,
  // psums (fp32) at element 12M (512 KB inside dead Wq).
  u16* Xq  = ws16;
  u16* Wq  = ws16 + 12 * MEG;
  u16* Wo  = ws16 + 15 * MEG;
  u16* Qp  = ws16 + 16 * MEG;
  u16* Kp  = ws16 + 20 * MEG;
  u16* Vt  = ws16 + 24 * MEG;
  u16* OpA = ws16;             // alias Xq
  u16* OpB = ws16 + 8 * MEG;   // alias Xv
  float* psAB = (float*)(ws16 + 12 * MEG);  // alias Wq (2 x 65536 floats)

  cvt7<<<dim3(4096), dim3(256), 0, stream>>>(q, k, v, wq, wk, wv, wo, ws16);

  // m-tiles on x (32), n-tiles on y (8): consecutive blocks share the B tile
  gemm_proj<<<dim3(32, 8, 3), dim3(256), 0, stream>>>(
      Xq, Wq, Qp, Vt, 1024, (long)(4 * MEG), (long)MEG, (long)(4 * MEG));

  attn_kernel<<<dim3(16, 32, 2), dim3(256), 0, stream>>>(Qp, Kp, Vt, mk, OpA, psAB);

  gemm_out_fused<<<dim3(64, 8), dim3(256), 0, stream>>>(
      OpA, OpB, psAB, psAB + 65536, Wo, bo, (float*)d_out);
}

// Round 3
// 214.744 us; speedup vs baseline: 2.0696x; 2.0696x over previous
//
#include <hip/hip_runtime.h>

typedef unsigned short u16;
typedef __bf16 bf16x8 __attribute__((ext_vector_type(8)));
typedef __bf16 bf16x4 __attribute__((ext_vector_type(4)));
typedef float floatx4 __attribute__((ext_vector_type(4)));
typedef u16 u16x4 __attribute__((ext_vector_type(4)));
typedef unsigned uint32x2 __attribute__((ext_vector_type(2)));
typedef unsigned uint32x4 __attribute__((ext_vector_type(4)));

#define MEG ((size_t)(1u << 20))

__device__ __forceinline__ u16 f2bf(float f) {
  unsigned int u = __float_as_uint(f);
  u += 0x7fffu + ((u >> 16) & 1u);   // round-to-nearest-even
  return (u16)(u >> 16);
}

// v_cvt_pk_bf16_f32: packs (lo,hi) -> one u32 of 2 bf16 (no builtin on gfx950)
__device__ __forceinline__ unsigned cvt_pk_bf16(float lo, float hi) {
  unsigned r;
  asm("v_cvt_pk_bf16_f32 %0, %1, %2" : "=v"(r) : "v"(lo), "v"(hi));
  return r;
}

// async global->LDS, 16B per lane; LDS dest = wave-uniform base + lane*16
__device__ __forceinline__ void load_lds16(const u16* g, u16* l) {
  __builtin_amdgcn_global_load_lds((const __attribute__((address_space(1))) unsigned int*)g,
                                   (__attribute__((address_space(3))) unsigned int*)l,
                                   16, 0, 0);
}

// ---------------- fp32 -> bf16 conversion of the 7 fp32 inputs ----------------
// layout (elements): [q 4M][k 4M][v 4M][Wq 1M][Wk 1M][Wv 1M][Wo 1M] = 16M
// 16 elems/thread (4 independent float4 loads) for memory-level parallelism.
__global__ __launch_bounds__(256) void cvt7(
    const float* __restrict__ s0, const float* __restrict__ s1,
    const float* __restrict__ s2, const float* __restrict__ s3,
    const float* __restrict__ s4, const float* __restrict__ s5,
    const float* __restrict__ s6, u16* __restrict__ dst)
{
  size_t e = ((size_t)blockIdx.x * 256 + threadIdx.x) * 16;
  unsigned m = (unsigned)(e >> 20);
  const float* s; size_t off;
  if (m < 4)       { s = s0; off = e; }
  else if (m < 8)  { s = s1; off = e - 4 * MEG; }
  else if (m < 12) { s = s2; off = e - 8 * MEG; }
  else if (m < 13) { s = s3; off = e - 12 * MEG; }
  else if (m < 14) { s = s4; off = e - 13 * MEG; }
  else if (m < 15) { s = s5; off = e - 14 * MEG; }
  else             { s = s6; off = e - 15 * MEG; }
  float4 f[4];
#pragma unroll
  for (int t = 0; t < 4; ++t)
    f[t] = *reinterpret_cast<const float4*>(s + off + t * 4);
#pragma unroll
  for (int t = 0; t < 4; ++t) {
    u16x4 o;
    o.x = f2bf(f[t].x); o.y = f2bf(f[t].y); o.z = f2bf(f[t].z); o.w = f2bf(f[t].w);
    *reinterpret_cast<u16x4*>(dst + e + t * 4) = o;
  }
}

// ---------------- generic C = A * B^T bf16 MFMA GEMM, BK=64 (projections) ----
// A: MxK bf16 row-major, B: NxK bf16 row-major. Tile 128x128, 4 waves (2x2).
// m-tile on blockIdx.x so consecutive dispatch ids share the B (weight) tile.
// xor-chunk-swizzled LDS (slot = c ^ (row&7)), conflict-free b128 frag reads.
// blockIdx.z==2 writes the transposed-per-head layout Vt[bh][d][l] instead.
__global__ __launch_bounds__(256) void gemm_proj(
    const u16* __restrict__ Abase, const u16* __restrict__ Bbase,
    u16* __restrict__ Cbase, u16* __restrict__ VtB,
    int K, long zA, long zB, long zC)
{
  __shared__ __align__(16) u16 As[128 * 64];
  __shared__ __align__(16) u16 Bs[128 * 64];
  const int tid = threadIdx.x;
  const int w = tid >> 6, ln = tid & 63;
  const int lm = ln & 15, lq = ln >> 4;
  const int wm = w >> 1, wn = w & 1;
  const long m0 = (long)blockIdx.x * 128, n0 = (long)blockIdx.y * 128;
  const u16* A = Abase + (size_t)blockIdx.z * (size_t)zA;
  const u16* B = Bbase + (size_t)blockIdx.z * (size_t)zB;

  const int r0 = tid >> 3;
  const int kc = (tid & 7) ^ (r0 & 7);
  const u16* gA = A + (m0 + r0) * (long)K + kc * 8;
  const u16* gB = B + (n0 + r0) * (long)K + kc * 8;
  const long rstep = 32L * K;

  const int sl0 = (lq ^ (lm & 7)) * 8;
  const int sl1 = ((4 + lq) ^ (lm & 7)) * 8;
  const u16* ab0 = &As[(wm * 64 + lm) * 64 + sl0];
  const u16* ab1 = &As[(wm * 64 + lm) * 64 + sl1];
  const u16* bb0 = &Bs[(wn * 64 + lm) * 64 + sl0];
  const u16* bb1 = &Bs[(wn * 64 + lm) * 64 + sl1];

  const floatx4 z4 = {0.f, 0.f, 0.f, 0.f};
  floatx4 acc[4][4];
#pragma unroll
  for (int i = 0; i < 4; ++i)
#pragma unroll
    for (int j = 0; j < 4; ++j) acc[i][j] = z4;

  for (int k0 = 0; k0 < K; k0 += 64) {
#pragma unroll
    for (int t = 0; t < 4; ++t) {
      load_lds16(gA + t * rstep, &As[(t * 256 + w * 64) * 8]);
      load_lds16(gB + t * rstep, &Bs[(t * 256 + w * 64) * 8]);
    }
    gA += 64; gB += 64;
    __syncthreads();
    bf16x8 af[4][2], bfr[4][2];
#pragma unroll
    for (int i = 0; i < 4; ++i) {
      af[i][0] = *reinterpret_cast<const bf16x8*>(ab0 + i * 1024);
      af[i][1] = *reinterpret_cast<const bf16x8*>(ab1 + i * 1024);
    }
#pragma unroll
    for (int j = 0; j < 4; ++j) {
      bfr[j][0] = *reinterpret_cast<const bf16x8*>(bb0 + j * 1024);
      bfr[j][1] = *reinterpret_cast<const bf16x8*>(bb1 + j * 1024);
    }
#pragma unroll
    for (int i = 0; i < 4; ++i)
#pragma unroll
      for (int j = 0; j < 4; ++j) {
        acc[i][j] = __builtin_amdgcn_mfma_f32_16x16x32_bf16(af[i][0], bfr[j][0], acc[i][j], 0, 0, 0);
        acc[i][j] = __builtin_amdgcn_mfma_f32_16x16x32_bf16(af[i][1], bfr[j][1], acc[i][j], 0, 0, 0);
      }
    __syncthreads();
  }

  if (blockIdx.z == 2) {
    // write V^T per head: Vt[(b*16+h)][d][l]; r=0..3 -> consecutive l -> one b64
#pragma unroll
    for (int i = 0; i < 4; ++i) {
      long row = m0 + wm * 64 + i * 16 + lq * 4;          // row = b*2048 + l
      int bq = (int)(row >> 11);
      int l  = (int)(row & 2047);
#pragma unroll
      for (int j = 0; j < 4; ++j) {
        long col = n0 + wn * 64 + j * 16 + lm;            // col = h*64 + d
        int hh = (int)(col >> 6), dd = (int)(col & 63);
        u16x4 o;
        o.x = f2bf(acc[i][j][0]); o.y = f2bf(acc[i][j][1]);
        o.z = f2bf(acc[i][j][2]); o.w = f2bf(acc[i][j][3]);
        *reinterpret_cast<u16x4*>(&VtB[((size_t)(bq * 16 + hh)) * 131072 +
                                       (size_t)dd * 2048 + l]) = o;
      }
    }
    return;
  }

#pragma unroll
  for (int i = 0; i < 4; ++i) {
    long row = m0 + wm * 64 + i * 16 + lq * 4;
#pragma unroll
    for (int j = 0; j < 4; ++j) {
      long col = n0 + wn * 64 + j * 16 + lm;
#pragma unroll
      for (int r = 0; r < 4; ++r) {
        size_t idx = (size_t)(row + r) * 1024 + (size_t)col;
        (Cbase + (size_t)blockIdx.z * (size_t)zC)[idx] = f2bf(acc[i][j][r]);
      }
    }
  }
}

// ---------------- out GEMM with FUSED K-split combine + normalize ------------
// C = ((OpA+OpB)*inv) @ Wo^T + bo, fp32 out. A K-tile (64) == one head h=k0>>6,
// so inv = 1/(psA[ql]+psB[ql]) is uniform per (row, k-iter): computed inline.
// A staged manually (load 2x b128 -> combine -> ds_write at DMA-equivalent
// swizzled slot); B staged via DMA. Tile 64x128, grid (64 m, 8 n).
__global__ __launch_bounds__(256) void gemm_out_fused(
    const u16* __restrict__ OpA, const u16* __restrict__ OpB,
    const float* __restrict__ psA, const float* __restrict__ psB,
    const u16* __restrict__ Wo, const float* __restrict__ bias,
    float* __restrict__ Cout)
{
  __shared__ __align__(16) u16 As[64 * 64];
  __shared__ __align__(16) u16 Bs[128 * 64];
  const int tid = threadIdx.x;
  const int w = tid >> 6, ln = tid & 63;
  const int lm = ln & 15, lq = ln >> 4;
  const int wm = w >> 1, wn = w & 1;
  const long m0 = (long)blockIdx.x * 64, n0 = (long)blockIdx.y * 128;

  const int r0 = tid >> 3;
  const int kc = (tid & 7) ^ (r0 & 7);
  const u16* gB = Wo + (n0 + r0) * 1024 + kc * 8;
  const long rstep = 32L * 1024;

  const int sl0 = (lq ^ (lm & 7)) * 8;
  const int sl1 = ((4 + lq) ^ (lm & 7)) * 8;
  const u16* ab0 = &As[(wm * 32 + lm) * 64 + sl0];
  const u16* ab1 = &As[(wm * 32 + lm) * 64 + sl1];
  const u16* bb0 = &Bs[(wn * 64 + lm) * 64 + sl0];
  const u16* bb1 = &Bs[(wn * 64 + lm) * 64 + sl1];

  // A-staging row info (2 rows per thread, 32 apart)
  int rowg[2]; int qlb[2];
#pragma unroll
  for (int t = 0; t < 2; ++t) {
    rowg[t] = (int)m0 + r0 + t * 32;                 // b*2048 + l
    int b = rowg[t] >> 11, l = rowg[t] & 2047;
    qlb[t] = (b << 4) * 2048 + l;                    // + h*2048 added per iter
  }

  const floatx4 z4 = {0.f, 0.f, 0.f, 0.f};
  floatx4 acc[2][4];
#pragma unroll
  for (int i = 0; i < 2; ++i)
#pragma unroll
    for (int j = 0; j < 4; ++j) acc[i][j] = z4;

  for (int k0 = 0; k0 < 1024; k0 += 64) {
    // B via DMA
#pragma unroll
    for (int t = 0; t < 4; ++t)
      load_lds16(gB + t * rstep, &Bs[(t * 256 + w * 64) * 8]);
    gB += 64;
    // A manual: combine K-split partials + normalize, write swizzled slot
    const int h = k0 >> 6;
#pragma unroll
    for (int t = 0; t < 2; ++t) {
      int ql = qlb[t] + h * 2048;
      float s = psA[ql] + psB[ql];
      float inv = (s > 0.f) ? __builtin_amdgcn_rcpf(s) : 0.f;
      size_t idx = (size_t)rowg[t] * 1024 + k0 + kc * 8;
      uint4 ua = *reinterpret_cast<const uint4*>(OpA + idx);
      uint4 ub = *reinterpret_cast<const uint4*>(OpB + idx);
      uint4 uo;
      const unsigned* pa = reinterpret_cast<const unsigned*>(&ua);
      const unsigned* pb = reinterpret_cast<const unsigned*>(&ub);
      unsigned* po = reinterpret_cast<unsigned*>(&uo);
#pragma unroll
      for (int i = 0; i < 4; ++i) {
        float alo = __uint_as_float(pa[i] << 16);
        float ahi = __uint_as_float(pa[i] & 0xFFFF0000u);
        float blo = __uint_as_float(pb[i] << 16);
        float bhi = __uint_as_float(pb[i] & 0xFFFF0000u);
        float olo = (alo + blo) * inv;
        float ohi = (ahi + bhi) * inv;
        po[i] = (unsigned)f2bf(olo) | ((unsigned)f2bf(ohi) << 16);
      }
      *reinterpret_cast<uint4*>(&As[(size_t)(t * 256 + tid) * 8]) = uo;
    }
    __syncthreads();
    bf16x8 af[2][2], bfr[4][2];
#pragma unroll
    for (int i = 0; i < 2; ++i) {
      af[i][0] = *reinterpret_cast<const bf16x8*>(ab0 + i * 1024);
      af[i][1] = *reinterpret_cast<const bf16x8*>(ab1 + i * 1024);
    }
#pragma unroll
    for (int j = 0; j < 4; ++j) {
      bfr[j][0] = *reinterpret_cast<const bf16x8*>(bb0 + j * 1024);
      bfr[j][1] = *reinterpret_cast<const bf16x8*>(bb1 + j * 1024);
    }
#pragma unroll
    for (int i = 0; i < 2; ++i)
#pragma unroll
      for (int j = 0; j < 4; ++j) {
        acc[i][j] = __builtin_amdgcn_mfma_f32_16x16x32_bf16(af[i][0], bfr[j][0], acc[i][j], 0, 0, 0);
        acc[i][j] = __builtin_amdgcn_mfma_f32_16x16x32_bf16(af[i][1], bfr[j][1], acc[i][j], 0, 0, 0);
      }
    __syncthreads();
  }

#pragma unroll
  for (int i = 0; i < 2; ++i) {
    long row = m0 + wm * 32 + i * 16 + lq * 4;
#pragma unroll
    for (int j = 0; j < 4; ++j) {
      long col = n0 + wn * 64 + j * 16 + lm;
      float bv = bias[col];
#pragma unroll
      for (int r = 0; r < 4; ++r)
        Cout[(size_t)(row + r) * 1024 + (size_t)col] = acc[i][j][r] + bv;
    }
  }
}

// ---------------- flash attention, K-split=2, double-buffered K/V ------------
// grid (16 q-tiles of 128, 32 bh, 2 K-halves) = 1024 blocks, 4 waves,
// 32 q-rows/wave (2 subtiles of 16), K-tile 64, 16 iters per block.
// R1 post-mortem: up-front kf/vf arrays pinned ~180 VGPRs -> spill, 5x slower.
// R2 post-mortem: phase restructure dropped the per-iter mask-pointer advance
// (mbi += 64) -> every K-tile used tile-0's mask -> absmax 6.9e-2 FAIL.
// R3 = R2 structure + the restored increment. Four short (m,h2) phases keep
// live regs < 128 cap; in-register P transpose (cvt_pk + permlane32/16_swap)
// keeps bank conflicts at 0; double-buffered K/V keeps 1 barrier/iter.
// LDS: 2*8KB K + 2*8KB V + 4KB mask = 36 KB -> 4 blocks/CU.
__global__ __launch_bounds__(256, 4) void attn_kernel(
    const u16* __restrict__ Qp, const u16* __restrict__ Kp,
    const u16* __restrict__ Vt, const int* __restrict__ mask,
    u16* __restrict__ OpBase, float* __restrict__ psAB)
{
  __shared__ __align__(16) u16 Ks[2 * 64 * 64];   // 16 KB, slot = c ^ (key&7)
  __shared__ __align__(16) u16 Vts[2 * 64 * 64];  // 16 KB, slot = c ^ (d&7)
  __shared__ __align__(16) float mball[1024];     // 4 KB mask bias fp32 (0/-inf)

  const int tid = threadIdx.x;
  const int w = tid >> 6, ln = tid & 63;
  const int lm = ln & 15, lq = ln >> 4;
  const int bh = blockIdx.y, b = bh >> 4, h = bh & 15;
  const int q0 = blockIdx.x * 128;
  const int kz = blockIdx.z;

  const u16* Qh = Qp + (size_t)b * 2048 * 1024 + h * 64;
  const u16* Kh = Kp + (size_t)b * 2048 * 1024 + (size_t)kz * 1024 * 1024 + h * 64;
  const u16* Vth = Vt + (size_t)bh * 64 * 2048 + kz * 1024;
  u16* Op = OpBase + (size_t)kz * 8 * MEG;
  float* psZ = psAB + (size_t)kz * 65536;

  // mask bias staged once (prologue __syncthreads covers visibility)
  const int* mrowp = mask + b * 2048 + kz * 1024;
#pragma unroll
  for (int t = 0; t < 4; ++t) {
    int i = t * 256 + tid;
    mball[i] = (mrowp[i] != 0) ? 0.f : -__builtin_inff();
  }

  // persistent Q fragments (B-operand for S^T), 2 q-subtiles
  bf16x8 qf[2][2];
#pragma unroll
  for (int m = 0; m < 2; ++m) {
    int qrow = q0 + w * 32 + m * 16 + lm;
    qf[m][0] = *reinterpret_cast<const bf16x8*>(Qh + (size_t)qrow * 1024 + lq * 8);
    qf[m][1] = *reinterpret_cast<const bf16x8*>(Qh + (size_t)qrow * 1024 + 32 + lq * 8);
  }

  // loop-invariant LDS pointers
  const int sl0 = (lq ^ (lm & 7)) * 8;
  const int sl1 = ((4 + lq) ^ (lm & 7)) * 8;
  const u16* kb0 = &Ks[lm * 64 + sl0];
  const u16* kb1 = &Ks[lm * 64 + sl1];
  const u16* vb0 = &Vts[lm * 64 + sl0];
  const u16* vb1 = &Vts[lm * 64 + sl1];
  const float* mbi = mball + lq * 4;

  // staging source running pointers (row r0 = tid>>3, chunk kc = (tid&7)^(r0&7))
  const int r0 = tid >> 3;
  const int kc = (tid & 7) ^ (r0 & 7);
  const u16* gK0 = Kh + (size_t)r0 * 1024 + kc * 8;
  const u16* gK1 = gK0 + 32 * 1024;
  const u16* gV0 = Vth + (size_t)r0 * 2048 + kc * 8;
  const u16* gV1 = gV0 + 32 * 2048;

  const floatx4 z4 = {0.f, 0.f, 0.f, 0.f};
  floatx4 O[2][4];
#pragma unroll
  for (int m = 0; m < 2; ++m)
#pragma unroll
    for (int j = 0; j < 4; ++j) O[m][j] = z4;
  float psum[2] = {0.f, 0.f};
  const float SCL = 0.18033688011112042f;  // log2(e) / sqrt(64)

  // prologue: stage tile 0 -> buffer 0
  load_lds16(gK0, &Ks[(w * 64) * 8]);
  load_lds16(gK1, &Ks[(256 + w * 64) * 8]);
  load_lds16(gV0, &Vts[(w * 64) * 8]);
  load_lds16(gV1, &Vts[(256 + w * 64) * 8]);
  gK0 += 64 * 1024; gK1 += 64 * 1024; gV0 += 64; gV1 += 64;
  __syncthreads();

  for (int it = 0; it < 16; ++it) {
    const int cur = it & 1;
    // issue tile t+1 DMA into the other buffer; end-of-iter barrier drains it
    if (it < 15) {
      const int nx = (cur ^ 1) * 4096;
      load_lds16(gK0, &Ks[nx + (w * 64) * 8]);
      load_lds16(gK1, &Ks[nx + (256 + w * 64) * 8]);
      load_lds16(gV0, &Vts[nx + (w * 64) * 8]);
      load_lds16(gV1, &Vts[nx + (256 + w * 64) * 8]);
      gK0 += 64 * 1024; gK1 += 64 * 1024; gV0 += 64; gV1 += 64;
    }
    const int bofs = cur * 4096;

#pragma unroll
    for (int m = 0; m < 2; ++m) {
#pragma unroll
      for (int h2 = 0; h2 < 2; ++h2) {
        // ---- phase (m,h2): keys 32*h2..32*h2+31 ----
        // QK^T: S^T for the 2 key-subtiles n=2*h2, 2*h2+1.
        // K-frags loaded here, dead after the 4 MFMAs (rematerializable).
        floatx4 S0, S1;
        {
          bf16x8 k00 = *reinterpret_cast<const bf16x8*>(kb0 + bofs + (2 * h2) * 1024);
          bf16x8 k01 = *reinterpret_cast<const bf16x8*>(kb1 + bofs + (2 * h2) * 1024);
          bf16x8 k10 = *reinterpret_cast<const bf16x8*>(kb0 + bofs + (2 * h2 + 1) * 1024);
          bf16x8 k11 = *reinterpret_cast<const bf16x8*>(kb1 + bofs + (2 * h2 + 1) * 1024);
          __builtin_amdgcn_s_setprio(1);
          S0 = __builtin_amdgcn_mfma_f32_16x16x32_bf16(k00, qf[m][0], z4, 0, 0, 0);
          S0 = __builtin_amdgcn_mfma_f32_16x16x32_bf16(k01, qf[m][1], S0, 0, 0, 0);
          S1 = __builtin_amdgcn_mfma_f32_16x16x32_bf16(k10, qf[m][0], z4, 0, 0, 0);
          S1 = __builtin_amdgcn_mfma_f32_16x16x32_bf16(k11, qf[m][1], S1, 0, 0, 0);
          __builtin_amdgcn_s_setprio(0);
        }

        // p = exp2(S*SCL + maskbias); pack to bf16 pairs; in-register
        // transpose: lane holds c[nn][j] = P[q=lm][key 16n+4lq+{2j,2j+1}];
        // A-frag needs pf = P[q=lm][key 32h2+8lq+e].  For each j:
        //   (P,Q) = permlane32_swap(c[0][j], c[1][j])
        //   (W[j], W[2+j]) = permlane16_swap(P, Q)
        float4 mbA = *reinterpret_cast<const float4*>(mbi + (2 * h2) * 16);
        float4 mbB = *reinterpret_cast<const float4*>(mbi + (2 * h2 + 1) * 16);
        float a0 = __builtin_amdgcn_exp2f(fmaf(S0[0], SCL, mbA.x));
        float a1 = __builtin_amdgcn_exp2f(fmaf(S0[1], SCL, mbA.y));
        float a2 = __builtin_amdgcn_exp2f(fmaf(S0[2], SCL, mbA.z));
        float a3 = __builtin_amdgcn_exp2f(fmaf(S0[3], SCL, mbA.w));
        psum[m] += (a0 + a1) + (a2 + a3);
        unsigned c00 = cvt_pk_bf16(a0, a1);
        unsigned c01 = cvt_pk_bf16(a2, a3);
        float b0 = __builtin_amdgcn_exp2f(fmaf(S1[0], SCL, mbB.x));
        float b1 = __builtin_amdgcn_exp2f(fmaf(S1[1], SCL, mbB.y));
        float b2 = __builtin_amdgcn_exp2f(fmaf(S1[2], SCL, mbB.z));
        float b3 = __builtin_amdgcn_exp2f(fmaf(S1[3], SCL, mbB.w));
        psum[m] += (b0 + b1) + (b2 + b3);
        unsigned c10 = cvt_pk_bf16(b0, b1);
        unsigned c11 = cvt_pk_bf16(b2, b3);

        uint32x2 t1a = __builtin_amdgcn_permlane32_swap(c00, c10, false, false);
        uint32x2 t2a = __builtin_amdgcn_permlane16_swap(t1a.x, t1a.y, false, false);
        uint32x2 t1b = __builtin_amdgcn_permlane32_swap(c01, c11, false, false);
        uint32x2 t2b = __builtin_amdgcn_permlane16_swap(t1b.x, t1b.y, false, false);
        uint32x4 wv = {t2a.x, t2b.x, t2a.y, t2b.y};
        bf16x8 pf = __builtin_bit_cast(bf16x8, wv);

        // PV: O += P(16x32 slice) * V; V-frags loaded at point of use.
        const u16* vb = (h2 ? vb1 : vb0) + bofs;
        __builtin_amdgcn_s_setprio(1);
#pragma unroll
        for (int j = 0; j < 4; ++j) {
          bf16x8 vfj = *reinterpret_cast<const bf16x8*>(vb + j * 1024);
          O[m][j] = __builtin_amdgcn_mfma_f32_16x16x32_bf16(pf, vfj, O[m][j], 0, 0, 0);
        }
        __builtin_amdgcn_s_setprio(0);
      }
    }
    mbi += 64;   // advance mask-bias to next key tile (R2's missing line)
    __syncthreads();
  }

  // epilogue: reduce psum over lq bits -> per-q total for this K-half;
  // store psum (lanes lq==0, consecutive rows -> coalesced) + raw O (bf16)
#pragma unroll
  for (int m = 0; m < 2; ++m) {
    float s = psum[m];
    s += __shfl_xor(s, 16, 64);
    s += __shfl_xor(s, 32, 64);
    int prow = q0 + w * 32 + m * 16 + lm;
    if (lq == 0) psZ[bh * 2048 + prow] = s;
#pragma unroll
    for (int r = 0; r < 4; ++r) {
      int row = q0 + w * 32 + m * 16 + lq * 4 + r;
      size_t base = ((size_t)b * 2048 + row) * 1024 + h * 64 + lm;
#pragma unroll
      for (int j = 0; j < 4; ++j)
        Op[base + j * 16] = f2bf(O[m][j][r]);
    }
  }
}

// ---------------- host ----------------
extern "C" void kernel_launch(void* const* d_in, const int* in_sizes, int n_in,
                              void* d_out, int out_size, void* d_ws, size_t ws_size,
                              hipStream_t stream) {
  const float* q  = (const float*)d_in[0];
  const float* k  = (const float*)d_in[1];
  const float* v  = (const float*)d_in[2];
  const int*   mk = (const int*)  d_in[3];
  const float* wq = (const float*)d_in[4];
  const float* wk = (const float*)d_in[5];
  const float* wv = (const float*)d_in[6];
  const float* wo = (const float*)d_in[7];
  const float* bo = (const float*)d_in[8];

  u16* ws16 = (u16*)d_ws;
  // element offsets (bf16): Xq=0 Xk=4M Xv=8M | Wq=12M Wk=13M Wv=14M Wo=15M
  // Qp=16M Kp=20M Vt=24M.
  // After proj: Xq/Xv/Wq..Wv dead -> OpA=0..4M, OpB=8..12M,
  // psums (fp32) at element 12M (512 KB inside dead Wq).
  u16* Xq  = ws16;
  u16* Wq  = ws16 + 12 * MEG;
  u16* Wo  = ws16 + 15 * MEG;
  u16* Qp  = ws16 + 16 * MEG;
  u16* Kp  = ws16 + 20 * MEG;
  u16* Vt  = ws16 + 24 * MEG;
  u16* OpA = ws16;             // alias Xq
  u16* OpB = ws16 + 8 * MEG;   // alias Xv
  float* psAB = (float*)(ws16 + 12 * MEG);  // alias Wq (2 x 65536 floats)

  cvt7<<<dim3(4096), dim3(256), 0, stream>>>(q, k, v, wq, wk, wv, wo, ws16);

  // m-tiles on x (32), n-tiles on y (8): consecutive blocks share the B tile
  gemm_proj<<<dim3(32, 8, 3), dim3(256), 0, stream>>>(
      Xq, Wq, Qp, Vt, 1024, (long)(4 * MEG), (long)MEG, (long)(4 * MEG));

  attn_kernel<<<dim3(16, 32, 2), dim3(256), 0, stream>>>(Qp, Kp, Vt, mk, OpA, psAB);

  gemm_out_fused<<<dim3(64, 8), dim3(256), 0, stream>>>(
      OpA, OpB, psAB, psAB + 65536, Wo, bo, (float*)d_out);
}